// Round 10
// baseline (140.907 us; speedup 1.0000x reference)
//
#include <hip/hip_runtime.h>
#include <math.h>

// Problem constants (B, CIN, COUT, K, S, P, D) = (4,128,128,3,1,1,1), H=W=96
#define HH 96
#define WW 96
#define HW (96*96)
#define CIN_ 128
#define COUT_ 128
#define OUT_ELEMS (4*128*96*96)
#define TPX 16            // pixels per conv block: 2304 blocks = 9/CU

// ws layout (bytes)
#define XT_OFF   0u           // x_t bf16 [4][9216][128] = 9,437,184 B
#define WBF_OFF  9437184u     // wbf FRAGMENT-ORDER bf16 [kc][kst][mt8][64][8] = 294,912 B
#define WOMB_OFF 9732096u     // womb FRAGMENT-ORDER bf16 [mt2][kc][kst][64][8] = 73,728 B

typedef __attribute__((ext_vector_type(8))) short short8v;
typedef __attribute__((ext_vector_type(4))) float float4v;

__device__ __forceinline__ unsigned short f2bf(float f) {
    unsigned u = __builtin_bit_cast(unsigned, f);
    u += 0x7FFFu + ((u >> 16) & 1u);   // RNE (inputs finite)
    return (unsigned short)(u >> 16);
}
__device__ __forceinline__ unsigned rneu(float f) {
    unsigned u = __builtin_bit_cast(unsigned, f);
    return u + 0x7FFFu + ((u >> 16) & 1u);
}
// pack bf16(hi)<<16 | bf16(lo) in one v_perm_b32 (bit-identical to f2bf pair)
__device__ __forceinline__ unsigned pkbf(float hi, float lo) {
    return __builtin_amdgcn_perm(rneu(hi), rneu(lo), 0x07060302u);
}
__device__ __forceinline__ float bflo(unsigned u) {
    return __builtin_bit_cast(float, u << 16);
}
__device__ __forceinline__ float bfhi(unsigned u) {
    return __builtin_bit_cast(float, u & 0xffff0000u);
}

// Raw block barrier: drains LDS ops only (lgkmcnt); pending global loads
// stay in flight (proven rounds 6-9).  sched_barrier(0) pins code motion.
#define BLOCK_SYNC() do {                                   \
    __builtin_amdgcn_sched_barrier(0);                      \
    asm volatile("s_waitcnt lgkmcnt(0)" ::: "memory");      \
    __builtin_amdgcn_s_barrier();                           \
    __builtin_amdgcn_sched_barrier(0);                      \
} while (0)

// ---------------------------------------------------------------------------
// Merged prep: blocks [0,576) transpose x -> x_t bf16 (XCD-aligned tiles);
// blocks [576,1296) convert weights to bf16 in MFMA FRAGMENT ORDER.
//   wbf : frag F = kc*32 + kst*8 + mt8 (mt8=oc>>4); lane l holds
//         (row=l&15, c = kst*32 + (l>>4)*8 + e).  This ordering lets the
//         conv kernel address all 16 A-frags of one kc with 4 base-adds +
//         literal offsets (mt stride 1KB, kst stride 8KB, kc stride 32KB).
//   womb: [mt2][kc][kst] (unchanged from round 9), rows>=27 zero.
// ---------------------------------------------------------------------------
__global__ __launch_bounds__(256) void pre_kernel(
    const float* __restrict__ x, const float* __restrict__ w,
    const float* __restrict__ wom, unsigned short* __restrict__ xt,
    unsigned short* __restrict__ wbf, unsigned short* __restrict__ womb)
{
    __shared__ float tile[64][130];
    const int t = threadIdx.x;
    const int f = blockIdx.x;

    if (f < 576) {
        const int g  = (f & 7) * 72 + (f >> 3);      // bijective [0,576)
        const int b  = g / 144;
        const int p0 = (g - b * 144) * 64;
#pragma unroll
        for (int j = 0; j < 8; j++) {               // read: 4 px per thread (float4)
            const int i  = j * 256 + t;
            const int c  = i >> 4;
            const int p4 = (i & 15) * 4;
            const float4 v = *(const float4*)(x + ((size_t)(b * CIN_ + c) * HW + p0 + p4));
            tile[p4 + 0][c] = v.x; tile[p4 + 1][c] = v.y;
            tile[p4 + 2][c] = v.z; tile[p4 + 3][c] = v.w;
        }
        __syncthreads();
#pragma unroll
        for (int j = 0; j < 8; j++) {               // write: 4 c per thread (8 B bf16)
            const int i   = j * 256 + t;
            const int pxl = i >> 5;
            const int c4  = (i & 31) * 4;
            uint2 v;
            v.x = pkbf(tile[pxl][c4 + 1], tile[pxl][c4 + 0]);
            v.y = pkbf(tile[pxl][c4 + 3], tile[pxl][c4 + 2]);
            *(uint2*)(xt + ((size_t)(b * HW + p0 + pxl) * CIN_ + c4)) = v;
        }
    } else {
        const int i = (f - 576) * 256 + t;          // [0, 184320)
        if (i < 147456) {                           // wbf frags, [kc][kst][mt8]
            const int F    = i >> 9;
            const int lane = (i >> 3) & 63;
            const int e    = i & 7;
            const int kc  = F >> 5;
            const int r   = F & 31;
            const int kst = r >> 3;
            const int mt8 = r & 7;
            const int oc  = mt8 * 16 + (lane & 15);
            const int c   = kst * 32 + (lane >> 4) * 8 + e;
            wbf[i] = f2bf(w[(size_t)oc * 1152 + c * 9 + kc]);
        } else {
            const int i2 = i - 147456;              // [0, 36864): womb frags
            const int frag = i2 >> 9;               // mt*36 + kc*4 + kst, mt<2
            const int lane = (i2 >> 3) & 63;
            const int e    = i2 & 7;
            const int mt = frag / 36, r = frag - mt * 36;
            const int kc = r >> 2, kst = r & 3;
            const int row = mt * 16 + (lane & 15);
            const int c   = kst * 32 + (lane >> 4) * 8 + e;
            womb[i2] = (row < 27) ? f2bf(wom[(size_t)row * 1152 + c * 9 + kc]) : 0;
        }
    }
}

// ---------------------------------------------------------------------------
// Small-block fused conv.  Grid 2304 (XCD-aligned), 128 thr (2 waves),
// 16 px / block = 9 blocks/CU (structure proven round 9; this round is
// instruction-count + critical-path polish):
//   phase 0a: stage 3x18 halo via global_load_lds (direct-to-LDS, source
//             pre-swizzled so linear dest == XOR layout; OOB rows zeroed
//             by disjoint predicated ds_writes).
//   phase 0b: om = womb @ halo with FOUR kst-split accumulators (chain
//             depth 36 -> 9), merged by 12 f32 adds -> som + off_out.
//   phase 1:  prep 144 items -> sprep; corner ids stored PRE-SHIFTED <<8.
//   phase 2:  per kc: register-pipelined coalesced gather (4 slots,
//             consume-then-reissue one kc ahead) -> swizzled btile[kc&1];
//             BLOCK_SYNC (lgkm-only); 4 kst x 4 mt MFMA, A-frags at
//             [kc][kst][mt8] layout = 4 base-adds + literal offsets per kc.
// LDS pool 3632 dw = 14528 B: staging [0,3456) dies after om; btile0
// [0,1024) btile1 [1024,2048) sprep [2048,3200) som [3200,3632).
// ---------------------------------------------------------------------------
__global__ __launch_bounds__(128, 4) void dconv_small(
    const unsigned short* __restrict__ xt, const unsigned short* __restrict__ wbf,
    const unsigned short* __restrict__ womb, const float* __restrict__ bias,
    float* __restrict__ out, float* __restrict__ off_out)
{
    __shared__ int smem[3632];            // 14528 B
    int*   btile0 = smem;                 // [16*64]
    int*   btile1 = smem + 1024;          // [16*64]
    int*   sprep  = smem + 2048;          // [144*8]
    float* som    = (float*)(smem + 3200);// [27][16]

    const int t    = threadIdx.x;         // 128
    const int wave = __builtin_amdgcn_readfirstlane(t >> 6);
    const int lane = t & 63;
    const int quad = lane >> 4;
    const int m    = lane & 15;
    const int l32  = lane & 31;
    const int half = lane >> 5;

    const int f  = blockIdx.x;
    const int c2 = (f & 7) * 288 + (f >> 3);         // XCD-aligned bijection [0,2304)
    const int b  = c2 / 576;
    const int p0 = (c2 - b * 576) * TPX;

    const unsigned short* xtb = xt + (size_t)b * HW * CIN_;
    const char* xtB = (const char*)xtb;

    const int h  = p0 / 96;
    const int w0 = p0 - h * 96;

    // ---- phase 0a: stage 3x18 zero-padded halo via global_load_lds --------
    // element i (16B) = row (i>>4) chunk (i&15); LDS dest is LINEAR
    // (wave-uniform base + lane*16); swizzle achieved by loading global
    // chunk (lin ^ (row&7)) into linear slot lin (involution).  OOB rows
    // get zeros via ds_write (disjoint slots, no ordering hazard).
#pragma unroll
    for (int k = 0; k < 7; k++) {
        const int i = k * 128 + t;
        if (i < 864) {
            const int row = i >> 4;
            const int lin = i & 15;
            const int r   = row / 18;
            const int cc  = row - r * 18;
            const int y   = h + r - 1;
            const int xx  = w0 + cc - 1;
            if (((unsigned)y < 96u) && ((unsigned)xx < 96u)) {
                const unsigned short* gsrc = xtb
                    + (size_t)(y * 96 + xx) * CIN_ + (lin ^ (row & 7)) * 8;
                __builtin_amdgcn_global_load_lds(
                    (const __attribute__((address_space(1))) unsigned int*)gsrc,
                    (__attribute__((address_space(3))) unsigned int*)
                        (smem + (k * 128 + wave * 64) * 4),
                    16, 0, 0);
            } else {
                *(int4*)&smem[i * 4] = make_int4(0, 0, 0, 0);
            }
        }
    }
    __syncthreads();                      // drains vmcnt (gload) + lgkm (zeros)

    // ---- phase 0b: om (wave = m-tile mt); 4 kst-split accumulators --------
    float4v acg[4];
#pragma unroll
    for (int j = 0; j < 4; j++)
#pragma unroll
        for (int r = 0; r < 4; r++) acg[j][r] = 0.f;
    {
        const short* wfB = (const short*)womb + (size_t)wave * 36 * 512 + lane * 8;
#pragma unroll
        for (int kc = 0; kc < 9; kc++) {
            const int ki = kc / 3, kj = kc - 3 * (kc / 3);
            const int sr = ki * 18 + m + kj;          // staged row 0..53
            const short* brow = (const short*)smem + sr * 128;
#pragma unroll
            for (int kst = 0; kst < 4; kst++) {
                const int c16s = (kst * 4 + quad) ^ (sr & 7);
                const short8v bfv = *(const short8v*)(brow + c16s * 8);
                const short8v av  = *(const short8v*)(wfB + (kc * 4 + kst) * 512);
                acg[kst] = __builtin_amdgcn_mfma_f32_16x16x32_bf16(av, bfv, acg[kst], 0, 0, 0);
            }
        }
    }
    __syncthreads();                      // all staging reads done

    {
#pragma unroll
        for (int r = 0; r < 4; r++) {
            const float v = (acg[0][r] + acg[1][r]) + (acg[2][r] + acg[3][r]);
            const int oc = wave * 16 + quad * 4 + r;
            if (oc < 27) som[oc * 16 + m] = v;
            if (oc < 18) off_out[(size_t)(b * 18 + oc) * HW + p0 + m] = v;
        }
    }
    __syncthreads();                      // som visible to both waves

    // ---- phase 1: prep 144 (kc,px) items -> sprep (ids pre-shifted <<8) ---
#pragma unroll
    for (int k = 0; k < 2; k++) {
        const int it = k * 128 + t;
        if (it < 144) {
            const int kc = it >> 4;
            const int px = it & 15;
            const int ki = kc / 3, kj = kc - 3 * (kc / 3);

            const float o1 = som[kc * 16 + px];
            const float o2 = som[(9 + kc) * 16 + px];
            const float mr = som[(18 + kc) * 16 + px];
            const float mk = 2.f / (1.f + __expf(-mr));   // sigmoid * MASK_SCALE

            const float py  = (float)(h - 1 + ki) + o1;
            const float pxf = (float)(w0 + px - 1 + kj) + o2;
            const float y0f = floorf(py), x0f = floorf(pxf);
            const float ly = py - y0f,    lx = pxf - x0f;
            const int y0 = (int)y0f, x0 = (int)x0f;
            const int y1 = y0 + 1,   x1 = x0 + 1;

            const float w00 = (1.f - ly) * (1.f - lx), w01 = (1.f - ly) * lx;
            const float w10 = ly * (1.f - lx),         w11 = ly * lx;

            const int yc0 = min(max(y0, 0), HH - 1), yc1 = min(max(y1, 0), HH - 1);
            const int xc0 = min(max(x0, 0), WW - 1), xc1 = min(max(x1, 0), WW - 1);
            const bool vy0 = (y0 >= 0) && (y0 < HH), vy1 = (y1 >= 0) && (y1 < HH);
            const bool vx0 = (x0 >= 0) && (x0 < WW), vx1 = (x1 >= 0) && (x1 < WW);

            sprep[it * 8 + 0] = (yc0 * 96 + xc0) << 8;
            sprep[it * 8 + 1] = (yc0 * 96 + xc1) << 8;
            sprep[it * 8 + 2] = (yc1 * 96 + xc0) << 8;
            sprep[it * 8 + 3] = (yc1 * 96 + xc1) << 8;
            sprep[it * 8 + 4] = __builtin_bit_cast(int, (vy0 && vx0) ? mk * w00 : 0.f);
            sprep[it * 8 + 5] = __builtin_bit_cast(int, (vy0 && vx1) ? mk * w01 : 0.f);
            sprep[it * 8 + 6] = __builtin_bit_cast(int, (vy1 && vx0) ? mk * w10 : 0.f);
            sprep[it * 8 + 7] = __builtin_bit_cast(int, (vy1 && vx1) ? mk * w11 : 0.f);
        }
    }
    __syncthreads();

    // ---- phase 2: pipelined coalesced gather + MFMA -----------------------
    uint2 gbuf[4][4];
    const unsigned co_ = (unsigned)l32 << 3;

#define ISSUE(SL, KCV, ITV) do {                                              \
    const int pxl_ = wave * 8 + (ITV) * 2 + half;                             \
    const int4 id4_ = *(const int4*)&sprep[((KCV) * 16 + pxl_) * 8];          \
    gbuf[SL][0] = *(const uint2*)(xtB + ((unsigned)id4_.x | co_));            \
    gbuf[SL][1] = *(const uint2*)(xtB + ((unsigned)id4_.y | co_));            \
    gbuf[SL][2] = *(const uint2*)(xtB + ((unsigned)id4_.z | co_));            \
    gbuf[SL][3] = *(const uint2*)(xtB + ((unsigned)id4_.w | co_));            \
} while (0)

#define COMBINE(SL, IV) do {                                                  \
    const int pxl_ = wave * 8 + (IV) * 2 + half;                              \
    const float4 w4_ = *(const float4*)&sprep[(kc * 16 + pxl_) * 8 + 4];      \
    const uint2 u0 = gbuf[SL][0], u1 = gbuf[SL][1];                           \
    const uint2 u2 = gbuf[SL][2], u3 = gbuf[SL][3];                           \
    const float v0 = w4_.x*bflo(u0.x) + w4_.y*bflo(u1.x) + w4_.z*bflo(u2.x) + w4_.w*bflo(u3.x); \
    const float v1 = w4_.x*bfhi(u0.x) + w4_.y*bfhi(u1.x) + w4_.z*bfhi(u2.x) + w4_.w*bfhi(u3.x); \
    const float v2 = w4_.x*bflo(u0.y) + w4_.y*bflo(u1.y) + w4_.z*bflo(u2.y) + w4_.w*bflo(u3.y); \
    const float v3 = w4_.x*bfhi(u0.y) + w4_.y*bfhi(u1.y) + w4_.z*bfhi(u2.y) + w4_.w*bfhi(u3.y); \
    uint2 o_;                                                                 \
    o_.x = pkbf(v1, v0);                                                      \
    o_.y = pkbf(v3, v2);                                                      \
    *(uint2*)&bt[pxl_ * 64 + (((l32 >> 1) ^ (pxl_ & 7)) << 2) + ((l32 & 1) << 1)] = o_; \
} while (0)

    float4v acc[4];
#pragma unroll
    for (int j = 0; j < 4; j++)
#pragma unroll
        for (int r = 0; r < 4; r++) acc[j][r] = 0.f;

    // A-fragment base: wave covers mt8 = wave*4 .. wave*4+3
    const char* aw = (const char*)wbf + ((size_t)wave << 12) + lane * 16;

    // prologue: all four iter-loads of kc=0 in flight
    ISSUE(0, 0, 0);
    ISSUE(1, 0, 1);
    ISSUE(2, 0, 2);
    ISSUE(3, 0, 3);

    for (int kc = 0; kc < 9; kc++) {
        int* bt = (kc & 1) ? btile1 : btile0;

        // consume slot, immediately reissue one kc ahead
        COMBINE(0, 0);
        if (kc < 8) ISSUE(0, kc + 1, 0);
        COMBINE(1, 1);
        if (kc < 8) ISSUE(1, kc + 1, 1);
        COMBINE(2, 2);
        if (kc < 8) ISSUE(2, kc + 1, 2);
        COMBINE(3, 3);
        if (kc < 8) ISSUE(3, kc + 1, 3);

        BLOCK_SYNC();   // lgkm-only: gather loads stay in flight

        // MFMA: 4 kst x 4 mt; A at [kc][kst][mt8] = base-add + imm offsets
        const char* ak = aw + kc * 32768;
#pragma unroll
        for (int kst = 0; kst < 4; kst++) {
            const short8v bfv = *(const short8v*)((const short*)bt
                + 2 * (m * 64 + (((kst * 4 + quad) ^ (m & 7)) << 2)));
            const char* aks = ak + kst * 8192;
#pragma unroll
            for (int mt = 0; mt < 4; mt++) {
                const short8v af = *(const short8v*)(aks + mt * 1024);
                acc[mt] = __builtin_amdgcn_mfma_f32_16x16x32_bf16(af, bfv, acc[mt], 0, 0, 0);
            }
        }
        // next kc writes the other buffer; this kc's ds_reads drain at the
        // next BLOCK_SYNC's lgkmcnt(0).
    }
#undef ISSUE
#undef COMBINE

    // ---- epilogue ---------------------------------------------------------
#pragma unroll
    for (int mt = 0; mt < 4; mt++) {
#pragma unroll
        for (int r = 0; r < 4; r++) {
            const int oc = wave * 64 + mt * 16 + quad * 4 + r;
            out[(size_t)(b * COUT_ + oc) * HW + p0 + m] = acc[mt][r] + bias[oc];
        }
    }
}

extern "C" void kernel_launch(void* const* d_in, const int* in_sizes, int n_in,
                              void* d_out, int out_size, void* d_ws, size_t ws_size,
                              hipStream_t stream) {
    const float* x      = (const float*)d_in[0];
    const float* weight = (const float*)d_in[1];
    const float* bias   = (const float*)d_in[2];
    const float* wom    = (const float*)d_in[3];

    float* out     = (float*)d_out;
    float* off_out = out + OUT_ELEMS;

    unsigned short* xtb  = (unsigned short*)((char*)d_ws + XT_OFF);
    unsigned short* wbf  = (unsigned short*)((char*)d_ws + WBF_OFF);
    unsigned short* womb = (unsigned short*)((char*)d_ws + WOMB_OFF);

    pre_kernel <<<dim3(1296), 256, 0, stream>>>(x, weight, wom, xtb, wbf, womb);
    dconv_small<<<dim3(2304), 128, 0, stream>>>(xtb, wbf, womb, bias, out, off_out);
}

// Round 11
// 131.744 us; speedup vs baseline: 1.0696x; 1.0696x over previous
//
#include <hip/hip_runtime.h>
#include <math.h>

// Problem constants (B, CIN, COUT, K, S, P, D) = (4,128,128,3,1,1,1), H=W=96
#define HH 96
#define WW 96
#define HW (96*96)
#define CIN_ 128
#define COUT_ 128
#define OUT_ELEMS (4*128*96*96)
#define TPX 16            // pixels per conv block: 2304 blocks = 9/CU

// ws layout (bytes)
#define XT_OFF   0u           // x_t bf16 [4][9216][128] = 9,437,184 B
#define WBF_OFF  9437184u     // wbf FRAGMENT-ORDER bf16 [288 frags][64 lanes][8] = 294,912 B
#define WOMB_OFF 9732096u     // womb FRAGMENT-ORDER bf16 [72 frags][64][8] = 73,728 B

typedef __attribute__((ext_vector_type(8))) short short8v;
typedef __attribute__((ext_vector_type(4))) float float4v;

__device__ __forceinline__ unsigned short f2bf(float f) {
    unsigned u = __builtin_bit_cast(unsigned, f);
    u += 0x7FFFu + ((u >> 16) & 1u);   // RNE (inputs finite)
    return (unsigned short)(u >> 16);
}
__device__ __forceinline__ unsigned rneu(float f) {
    unsigned u = __builtin_bit_cast(unsigned, f);
    return u + 0x7FFFu + ((u >> 16) & 1u);
}
// pack bf16(hi)<<16 | bf16(lo) in one v_perm_b32 (bit-identical to f2bf pair)
__device__ __forceinline__ unsigned pkbf(float hi, float lo) {
    return __builtin_amdgcn_perm(rneu(hi), rneu(lo), 0x07060302u);
}
__device__ __forceinline__ float bflo(unsigned u) {
    return __builtin_bit_cast(float, u << 16);
}
__device__ __forceinline__ float bfhi(unsigned u) {
    return __builtin_bit_cast(float, u & 0xffff0000u);
}

// Raw block barrier: drains LDS ops only (lgkmcnt); pending global loads
// stay in flight (proven rounds 6-9).  sched_barrier(0) pins code motion.
#define BLOCK_SYNC() do {                                   \
    __builtin_amdgcn_sched_barrier(0);                      \
    asm volatile("s_waitcnt lgkmcnt(0)" ::: "memory");      \
    __builtin_amdgcn_s_barrier();                           \
    __builtin_amdgcn_sched_barrier(0);                      \
} while (0)

// ---------------------------------------------------------------------------
// Merged prep: blocks [0,576) transpose x -> x_t bf16 (XCD-aligned tiles);
// blocks [576,1296) convert weights to bf16 in MFMA FRAGMENT ORDER:
//   wbf : frag F = mt*36 + kc*4 + kst  (mt=oc>>4), 64 lanes x 8 ch each --
//         lane l holds (row=l&15, c = kst*32 + (l>>4)*8 + e).  A-loads in
//         the conv kernel become ONE contiguous 1KB segment (no scatter).
//   womb: same layout, 72 frags (mt<2; rows>=27 zero).
// (byte-identical to round 9 — the proven 64.5 us configuration)
// ---------------------------------------------------------------------------
__global__ __launch_bounds__(256) void pre_kernel(
    const float* __restrict__ x, const float* __restrict__ w,
    const float* __restrict__ wom, unsigned short* __restrict__ xt,
    unsigned short* __restrict__ wbf, unsigned short* __restrict__ womb)
{
    __shared__ float tile[64][130];
    const int t = threadIdx.x;
    const int f = blockIdx.x;

    if (f < 576) {
        const int g  = (f & 7) * 72 + (f >> 3);      // bijective [0,576)
        const int b  = g / 144;
        const int p0 = (g - b * 144) * 64;
#pragma unroll
        for (int j = 0; j < 8; j++) {               // read: 4 px per thread (float4)
            const int i  = j * 256 + t;
            const int c  = i >> 4;
            const int p4 = (i & 15) * 4;
            const float4 v = *(const float4*)(x + ((size_t)(b * CIN_ + c) * HW + p0 + p4));
            tile[p4 + 0][c] = v.x; tile[p4 + 1][c] = v.y;
            tile[p4 + 2][c] = v.z; tile[p4 + 3][c] = v.w;
        }
        __syncthreads();
#pragma unroll
        for (int j = 0; j < 8; j++) {               // write: 4 c per thread (8 B bf16)
            const int i   = j * 256 + t;
            const int pxl = i >> 5;
            const int c4  = (i & 31) * 4;
            uint2 v;
            v.x = pkbf(tile[pxl][c4 + 1], tile[pxl][c4 + 0]);
            v.y = pkbf(tile[pxl][c4 + 3], tile[pxl][c4 + 2]);
            *(uint2*)(xt + ((size_t)(b * HW + p0 + pxl) * CIN_ + c4)) = v;
        }
    } else {
        const int i = (f - 576) * 256 + t;          // [0, 184320)
        if (i < 147456) {                           // wbf fragments
            const int frag = i >> 9;                // mt*36 + kc*4 + kst
            const int lane = (i >> 3) & 63;
            const int e    = i & 7;
            const int mt = frag / 36, r = frag - mt * 36;
            const int kc = r >> 2, kst = r & 3;
            const int m = lane & 15, quad = lane >> 4;
            const int oc = mt * 16 + m;
            const int c  = kst * 32 + quad * 8 + e;
            wbf[i] = f2bf(w[(size_t)oc * 1152 + c * 9 + kc]);
        } else {
            const int i2 = i - 147456;              // [0, 36864): womb fragments
            const int frag = i2 >> 9;               // mt*36 + kc*4 + kst, mt<2
            const int lane = (i2 >> 3) & 63;
            const int e    = i2 & 7;
            const int mt = frag / 36, r = frag - mt * 36;
            const int kc = r >> 2, kst = r & 3;
            const int m = lane & 15, quad = lane >> 4;
            const int row = mt * 16 + m;
            const int c   = kst * 32 + quad * 8 + e;
            womb[i2] = (row < 27) ? f2bf(wom[(size_t)row * 1152 + c * 9 + kc]) : 0;
        }
    }
}

// ---------------------------------------------------------------------------
// Small-block fused conv.  Grid 2304 (XCD-aligned), 128 thr (2 waves),
// 16 px / block = 9 blocks/CU.  ROUND-9 STRUCTURE (proven 64.5 us) with
// exactly two register-level changes:
//   (1) om accumulator split 4-way by kst: MFMA dep-chain 36 -> 9.
//   (2) sprep corner ids stored PRE-SHIFTED <<8: one shift+or fewer per
//       corner address in ISSUE.
// Everything else (staging, layouts, schedule, barriers) is byte-identical
// to round 9 for clean attribution.
// LDS pool 3632 dw = 14528 B: staging [0,3456) dies after om; btile0
// [0,1024) btile1 [1024,2048) sprep [2048,3200) som [3200,3632).
// ---------------------------------------------------------------------------
__global__ __launch_bounds__(128, 4) void dconv_small(
    const unsigned short* __restrict__ xt, const unsigned short* __restrict__ wbf,
    const unsigned short* __restrict__ womb, const float* __restrict__ bias,
    float* __restrict__ out, float* __restrict__ off_out)
{
    __shared__ int smem[3632];            // 14528 B
    int*   btile0 = smem;                 // [16*64]
    int*   btile1 = smem + 1024;          // [16*64]
    int*   sprep  = smem + 2048;          // [144*8]
    float* som    = (float*)(smem + 3200);// [27][16]

    const int t    = threadIdx.x;         // 128
    const int wave = __builtin_amdgcn_readfirstlane(t >> 6);
    const int lane = t & 63;
    const int quad = lane >> 4;
    const int m    = lane & 15;
    const int l32  = lane & 31;
    const int half = lane >> 5;

    const int f  = blockIdx.x;
    const int c2 = (f & 7) * 288 + (f >> 3);         // XCD-aligned bijection [0,2304)
    const int b  = c2 / 576;
    const int p0 = (c2 - b * 576) * TPX;

    const unsigned short* xtb = xt + (size_t)b * HW * CIN_;
    const char* xtB = (const char*)xtb;

    const int h  = p0 / 96;
    const int w0 = p0 - h * 96;

    // ---- phase 0a: stage 3x18 zero-padded halo (54 rows x 256B) -----------
    // row = r*18+cc -> image (y,xx) = (h-1+r, w0-1+cc); chunk ch at
    // ch^(row&7) (swizzle-matched to phase-0b reads).  Manual VGPR
    // round-trip staging (round-9 proven; burst of 864 coalesced loads).
#pragma unroll
    for (int k = 0; k < 7; k++) {
        const int i = k * 128 + t;
        if (i < 864) {
            const int row = i >> 4;
            const int ch  = i & 15;
            const int r   = row / 18;
            const int cc  = row - r * 18;
            const int y   = h + r - 1;
            const int xx  = w0 + cc - 1;
            uint4 v = make_uint4(0u, 0u, 0u, 0u);
            if (((unsigned)y < 96u) && ((unsigned)xx < 96u))
                v = *(const uint4*)(xtb + (size_t)(y * 96 + xx) * CIN_ + ch * 8);
            *(uint4*)&smem[row * 64 + ((ch ^ (row & 7)) << 2)] = v;
        }
    }
    __syncthreads();

    // ---- phase 0b: om (wave = m-tile mt); FOUR kst-split accumulators -----
    float4v acg[4];
#pragma unroll
    for (int j = 0; j < 4; j++)
#pragma unroll
        for (int r = 0; r < 4; r++) acg[j][r] = 0.f;
    {
        const short* wfB = (const short*)womb + (size_t)wave * 36 * 512 + lane * 8;
#pragma unroll
        for (int kc = 0; kc < 9; kc++) {
            const int ki = kc / 3, kj = kc - 3 * (kc / 3);
            const int sr = ki * 18 + m + kj;          // staged row 0..53
            const short* brow = (const short*)smem + sr * 128;
#pragma unroll
            for (int kst = 0; kst < 4; kst++) {
                const int c16s = (kst * 4 + quad) ^ (sr & 7);
                const short8v bfv = *(const short8v*)(brow + c16s * 8);
                const short8v av  = *(const short8v*)(wfB + (kc * 4 + kst) * 512);
                acg[kst] = __builtin_amdgcn_mfma_f32_16x16x32_bf16(av, bfv, acg[kst], 0, 0, 0);
            }
        }
    }
    __syncthreads();                      // all staging reads done

    {
#pragma unroll
        for (int r = 0; r < 4; r++) {
            const float v = (acg[0][r] + acg[1][r]) + (acg[2][r] + acg[3][r]);
            const int oc = wave * 16 + quad * 4 + r;
            if (oc < 27) som[oc * 16 + m] = v;
            if (oc < 18) off_out[(size_t)(b * 18 + oc) * HW + p0 + m] = v;
        }
    }
    __syncthreads();                      // som visible to both waves

    // ---- phase 1: prep 144 (kc,px) items -> sprep (ids pre-shifted <<8) ---
#pragma unroll
    for (int k = 0; k < 2; k++) {
        const int it = k * 128 + t;
        if (it < 144) {
            const int kc = it >> 4;
            const int px = it & 15;
            const int ki = kc / 3, kj = kc - 3 * (kc / 3);

            const float o1 = som[kc * 16 + px];
            const float o2 = som[(9 + kc) * 16 + px];
            const float mr = som[(18 + kc) * 16 + px];
            const float mk = 2.f / (1.f + __expf(-mr));   // sigmoid * MASK_SCALE

            const float py  = (float)(h - 1 + ki) + o1;
            const float pxf = (float)(w0 + px - 1 + kj) + o2;
            const float y0f = floorf(py), x0f = floorf(pxf);
            const float ly = py - y0f,    lx = pxf - x0f;
            const int y0 = (int)y0f, x0 = (int)x0f;
            const int y1 = y0 + 1,   x1 = x0 + 1;

            const float w00 = (1.f - ly) * (1.f - lx), w01 = (1.f - ly) * lx;
            const float w10 = ly * (1.f - lx),         w11 = ly * lx;

            const int yc0 = min(max(y0, 0), HH - 1), yc1 = min(max(y1, 0), HH - 1);
            const int xc0 = min(max(x0, 0), WW - 1), xc1 = min(max(x1, 0), WW - 1);
            const bool vy0 = (y0 >= 0) && (y0 < HH), vy1 = (y1 >= 0) && (y1 < HH);
            const bool vx0 = (x0 >= 0) && (x0 < WW), vx1 = (x1 >= 0) && (x1 < WW);

            sprep[it * 8 + 0] = (yc0 * 96 + xc0) << 8;
            sprep[it * 8 + 1] = (yc0 * 96 + xc1) << 8;
            sprep[it * 8 + 2] = (yc1 * 96 + xc0) << 8;
            sprep[it * 8 + 3] = (yc1 * 96 + xc1) << 8;
            sprep[it * 8 + 4] = __builtin_bit_cast(int, (vy0 && vx0) ? mk * w00 : 0.f);
            sprep[it * 8 + 5] = __builtin_bit_cast(int, (vy0 && vx1) ? mk * w01 : 0.f);
            sprep[it * 8 + 6] = __builtin_bit_cast(int, (vy1 && vx0) ? mk * w10 : 0.f);
            sprep[it * 8 + 7] = __builtin_bit_cast(int, (vy1 && vx1) ? mk * w11 : 0.f);
        }
    }
    __syncthreads();

    // ---- phase 2: pipelined coalesced gather + MFMA (round-9 schedule) ----
    uint2 gbuf[4][4];
    const unsigned co_ = (unsigned)l32 << 3;

#define ISSUE(SL, KCV, ITV) do {                                              \
    const int pxl_ = wave * 8 + (ITV) * 2 + half;                             \
    const int4 id4_ = *(const int4*)&sprep[((KCV) * 16 + pxl_) * 8];          \
    gbuf[SL][0] = *(const uint2*)(xtB + ((unsigned)id4_.x | co_));            \
    gbuf[SL][1] = *(const uint2*)(xtB + ((unsigned)id4_.y | co_));            \
    gbuf[SL][2] = *(const uint2*)(xtB + ((unsigned)id4_.z | co_));            \
    gbuf[SL][3] = *(const uint2*)(xtB + ((unsigned)id4_.w | co_));            \
} while (0)

#define COMBINE(SL, IV) do {                                                  \
    const int pxl_ = wave * 8 + (IV) * 2 + half;                              \
    const float4 w4_ = *(const float4*)&sprep[(kc * 16 + pxl_) * 8 + 4];      \
    const uint2 u0 = gbuf[SL][0], u1 = gbuf[SL][1];                           \
    const uint2 u2 = gbuf[SL][2], u3 = gbuf[SL][3];                           \
    const float v0 = w4_.x*bflo(u0.x) + w4_.y*bflo(u1.x) + w4_.z*bflo(u2.x) + w4_.w*bflo(u3.x); \
    const float v1 = w4_.x*bfhi(u0.x) + w4_.y*bfhi(u1.x) + w4_.z*bfhi(u2.x) + w4_.w*bfhi(u3.x); \
    const float v2 = w4_.x*bflo(u0.y) + w4_.y*bflo(u1.y) + w4_.z*bflo(u2.y) + w4_.w*bflo(u3.y); \
    const float v3 = w4_.x*bfhi(u0.y) + w4_.y*bfhi(u1.y) + w4_.z*bfhi(u2.y) + w4_.w*bfhi(u3.y); \
    uint2 o_;                                                                 \
    o_.x = pkbf(v1, v0);                                                      \
    o_.y = pkbf(v3, v2);                                                      \
    *(uint2*)&bt[pxl_ * 64 + (((l32 >> 1) ^ (pxl_ & 7)) << 2) + ((l32 & 1) << 1)] = o_; \
} while (0)

    float4v acc[4];
#pragma unroll
    for (int j = 0; j < 4; j++)
#pragma unroll
        for (int r = 0; r < 4; r++) acc[j][r] = 0.f;

    // A-fragment base: wave covers m-tiles wave*4 .. wave*4+3
    const char* wfrag = (const char*)wbf + ((size_t)wave * 4 * 36) * 1024 + lane * 16;

    // prologue: all four iter-loads of kc=0 in flight
    ISSUE(0, 0, 0);
    ISSUE(1, 0, 1);
    ISSUE(2, 0, 2);
    ISSUE(3, 0, 3);

    for (int kc = 0; kc < 9; kc++) {
        int* bt = (kc & 1) ? btile1 : btile0;

        // consume slot, immediately reissue one kc ahead
        COMBINE(0, 0);
        if (kc < 8) ISSUE(0, kc + 1, 0);
        COMBINE(1, 1);
        if (kc < 8) ISSUE(1, kc + 1, 1);
        COMBINE(2, 2);
        if (kc < 8) ISSUE(2, kc + 1, 2);
        COMBINE(3, 3);
        if (kc < 8) ISSUE(3, kc + 1, 3);

        BLOCK_SYNC();   // lgkm-only: gather loads stay in flight

        // MFMA: 4 kst x 4 mt; A = contiguous fragment loads, B = swizzled LDS
#pragma unroll
        for (int kst = 0; kst < 4; kst++) {
            const short8v bfv = *(const short8v*)((const short*)bt
                + 2 * (m * 64 + (((kst * 4 + quad) ^ (m & 7)) << 2)));
#pragma unroll
            for (int mt = 0; mt < 4; mt++) {
                const short8v af = *(const short8v*)(wfrag
                    + ((size_t)(mt * 36 + kc * 4 + kst)) * 1024);
                acc[mt] = __builtin_amdgcn_mfma_f32_16x16x32_bf16(af, bfv, acc[mt], 0, 0, 0);
            }
        }
        // next kc writes the other buffer; this kc's ds_reads drain at the
        // next BLOCK_SYNC's lgkmcnt(0).
    }
#undef ISSUE
#undef COMBINE

    // ---- epilogue ---------------------------------------------------------
#pragma unroll
    for (int mt = 0; mt < 4; mt++) {
#pragma unroll
        for (int r = 0; r < 4; r++) {
            const int oc = wave * 64 + mt * 16 + quad * 4 + r;
            out[(size_t)(b * COUT_ + oc) * HW + p0 + m] = acc[mt][r] + bias[oc];
        }
    }
}

extern "C" void kernel_launch(void* const* d_in, const int* in_sizes, int n_in,
                              void* d_out, int out_size, void* d_ws, size_t ws_size,
                              hipStream_t stream) {
    const float* x      = (const float*)d_in[0];
    const float* weight = (const float*)d_in[1];
    const float* bias   = (const float*)d_in[2];
    const float* wom    = (const float*)d_in[3];

    float* out     = (float*)d_out;
    float* off_out = out + OUT_ELEMS;

    unsigned short* xtb  = (unsigned short*)((char*)d_ws + XT_OFF);
    unsigned short* wbf  = (unsigned short*)((char*)d_ws + WBF_OFF);
    unsigned short* womb = (unsigned short*)((char*)d_ws + WOMB_OFF);

    pre_kernel <<<dim3(1296), 256, 0, stream>>>(x, weight, wom, xtb, wbf, womb);
    dconv_small<<<dim3(2304), 128, 0, stream>>>(xtb, wbf, womb, bias, out, off_out);
}